// Round 2
// baseline (1011.867 us; speedup 1.0000x reference)
//
#include <hip/hip_runtime.h>
#include <hip/hip_bf16.h>

// Problem constants (MoE grouped FFN, uniform groups)
#define NE 32      // experts
#define HD 2048    // hidden
#define ID 1024    // intermediate
#define GT 1024    // tokens per expert (T/E = 32768/32)

// Tile config
#define BM 128
#define BN 128
#define BK 64

typedef __attribute__((ext_vector_type(8))) __bf16 bf16x8;
typedef __attribute__((ext_vector_type(4))) float  f32x4;
typedef __attribute__((ext_vector_type(2))) float  f32x2;

__device__ __forceinline__ __bf16 f2b(float f) { return (__bf16)f; }

// ---------------------------------------------------------------------------
// Kernel 1: gate_up = x_e @ w13_e ; h = silu(gate)*up  (bf16 out to ws)
// 1-D grid 2048 = 32 experts x 8 m-tiles x 8 n-tiles, 256 threads (4 waves 2x2)
// LDS swizzle: A tile  As[row][ (oct ^ (row&7))*8 + j ]
//              B tiles Bg/Bu[row][ (oct ^ ((row>>1)&7))*8 + j ]
// ---------------------------------------------------------------------------
__global__ __launch_bounds__(256, 2)
void moe_gemm1_swiglu(const float* __restrict__ x,
                      const float* __restrict__ w13,
                      __bf16* __restrict__ h) {
  __shared__ __bf16 As[BM][BK];
  __shared__ __bf16 Bg[BN][BK];
  __shared__ __bf16 Bu[BN][BK];

  const int t = threadIdx.x;

  // XCD-aware chunked remap (2048 % 8 == 0 -> bijective).
  // Each XCD gets 4 whole experts; within an expert, order is n-major so the
  // 8 blocks sharing a w13 N-panel (2 MB, fits 4 MB L2) are temporally close.
  const int bid  = blockIdx.x;
  const int work = (bid & 7) * 256 + (bid >> 3);
  const int e    = work >> 6;
  const int rem  = work & 63;
  const int n0   = (rem >> 3) * BN;
  const int m0   = (rem & 7) * BM;

  const float* xA = x   + (size_t)(e * GT + m0) * HD;
  const float* wB = w13 + (size_t)e * HD * (2 * ID);

  const int wid = t >> 6, lane = t & 63;
  const int wm = wid >> 1, wn = wid & 1;
  const int fr = lane & 15, fq = lane >> 4;

  f32x4 accg[4][4];
  f32x4 accu[4][4];
#pragma unroll
  for (int i = 0; i < 4; ++i)
#pragma unroll
    for (int j = 0; j < 4; ++j) { accg[i][j] = 0.f; accu[i][j] = 0.f; }

  for (int k0 = 0; k0 < HD; k0 += BK) {
    // ---- stage A: lane owns (m, k16-chunk). 512 tasks, 2/thread.
    // loads: 4x f32x4 contiguous (64 B); writes: 2 swizzled b128 (conflict-free)
#pragma unroll
    for (int i = 0; i < 2; ++i) {
      int id = i * 256 + t;
      int m  = id >> 2, kq = id & 3;
      const float* src = xA + (size_t)m * HD + k0 + kq * 16;
      f32x4 va0 = *reinterpret_cast<const f32x4*>(src + 0);
      f32x4 va1 = *reinterpret_cast<const f32x4*>(src + 4);
      f32x4 va2 = *reinterpret_cast<const f32x4*>(src + 8);
      f32x4 va3 = *reinterpret_cast<const f32x4*>(src + 12);
      bf16x8 lo, hi;
      lo[0] = f2b(va0[0]); lo[1] = f2b(va0[1]); lo[2] = f2b(va0[2]); lo[3] = f2b(va0[3]);
      lo[4] = f2b(va1[0]); lo[5] = f2b(va1[1]); lo[6] = f2b(va1[2]); lo[7] = f2b(va1[3]);
      hi[0] = f2b(va2[0]); hi[1] = f2b(va2[1]); hi[2] = f2b(va2[2]); hi[3] = f2b(va2[3]);
      hi[4] = f2b(va3[0]); hi[5] = f2b(va3[1]); hi[6] = f2b(va3[2]); hi[7] = f2b(va3[3]);
      int s0 = ((kq * 2 + 0) ^ (m & 7)) * 8;
      int s1 = ((kq * 2 + 1) ^ (m & 7)) * 8;
      *reinterpret_cast<bf16x8*>(&As[m][s0]) = lo;
      *reinterpret_cast<bf16x8*>(&As[m][s1]) = hi;
    }
    // ---- stage B (gate & up): lane owns (n-pair, k-octet). 512 tasks, 2/thread.
    // loads: 8x f32x2 per matrix (64 lanes x 8B = 512 B contiguous/instr)
    // writes: 2 swizzled b128 per matrix (conflict-free: slot = ko ^ (np&7))
#pragma unroll
    for (int i = 0; i < 2; ++i) {
      int id = i * 256 + t;
      int np = id & 63, ko = id >> 6;
      const float* pg = wB + (size_t)(k0 + ko * 8) * (2 * ID) + (n0 + np * 2);
      f32x2 g[8], u[8];
#pragma unroll
      for (int j = 0; j < 8; ++j) {
        g[j] = *reinterpret_cast<const f32x2*>(pg + (size_t)j * (2 * ID));
        u[j] = *reinterpret_cast<const f32x2*>(pg + (size_t)j * (2 * ID) + ID);
      }
      int slot = (ko ^ (np & 7)) * 8;
      int r0 = np * 2, r1 = np * 2 + 1;
      bf16x8 v;
#pragma unroll
      for (int j = 0; j < 8; ++j) v[j] = f2b(g[j][0]);
      *reinterpret_cast<bf16x8*>(&Bg[r0][slot]) = v;
#pragma unroll
      for (int j = 0; j < 8; ++j) v[j] = f2b(g[j][1]);
      *reinterpret_cast<bf16x8*>(&Bg[r1][slot]) = v;
#pragma unroll
      for (int j = 0; j < 8; ++j) v[j] = f2b(u[j][0]);
      *reinterpret_cast<bf16x8*>(&Bu[r0][slot]) = v;
#pragma unroll
      for (int j = 0; j < 8; ++j) v[j] = f2b(u[j][1]);
      *reinterpret_cast<bf16x8*>(&Bu[r1][slot]) = v;
    }
    __syncthreads();
    // ---- MFMA ----
#pragma unroll
    for (int kk = 0; kk < BK; kk += 32) {
      const int kb = kk >> 3;   // 0 or 4 (16B-octet base)
      bf16x8 af[4], bgf[4], buf2[4];
#pragma unroll
      for (int mi = 0; mi < 4; ++mi) {
        int row = wm * 64 + mi * 16 + fr;
        int oct = (fq + kb) ^ (row & 7);
        af[mi] = *reinterpret_cast<const bf16x8*>(&As[row][oct * 8]);
      }
#pragma unroll
      for (int ni = 0; ni < 4; ++ni) {
        int row = wn * 64 + ni * 16 + fr;
        int oct = (fq + kb) ^ ((row >> 1) & 7);
        bgf[ni]  = *reinterpret_cast<const bf16x8*>(&Bg[row][oct * 8]);
        buf2[ni] = *reinterpret_cast<const bf16x8*>(&Bu[row][oct * 8]);
      }
#pragma unroll
      for (int mi = 0; mi < 4; ++mi)
#pragma unroll
        for (int ni = 0; ni < 4; ++ni) {
          accg[mi][ni] = __builtin_amdgcn_mfma_f32_16x16x32_bf16(af[mi], bgf[ni], accg[mi][ni], 0, 0, 0);
          accu[mi][ni] = __builtin_amdgcn_mfma_f32_16x16x32_bf16(af[mi], buf2[ni], accu[mi][ni], 0, 0, 0);
        }
    }
    __syncthreads();
  }

  // ---- epilogue: SwiGLU, write h (bf16) ----
#pragma unroll
  for (int mi = 0; mi < 4; ++mi)
#pragma unroll
    for (int ni = 0; ni < 4; ++ni)
#pragma unroll
      for (int j = 0; j < 4; ++j) {
        int row = m0 + wm * 64 + mi * 16 + fq * 4 + j;
        int col = n0 + wn * 64 + ni * 16 + fr;
        float g = accg[mi][ni][j];
        float u = accu[mi][ni][j];
        float s = g / (1.f + __expf(-g));
        h[(size_t)(e * GT + row) * ID + col] = f2b(s * u);
      }
}

// ---------------------------------------------------------------------------
// Kernel 2: out = h @ w2_e   (h bf16 [T][I], w2 f32 [E][I][H], out f32)
// 1-D grid 4096 = 32 experts x 8 m-tiles x 16 n-tiles, 256 threads
// ---------------------------------------------------------------------------
__global__ __launch_bounds__(256, 3)
void moe_gemm2(const __bf16* __restrict__ h,
               const float* __restrict__ w2,
               float* __restrict__ out) {
  __shared__ __bf16 As[BM][BK];
  __shared__ __bf16 Bs[BN][BK];

  const int t = threadIdx.x;

  const int bid  = blockIdx.x;
  const int work = (bid & 7) * 512 + (bid >> 3);
  const int e    = work >> 7;
  const int rem  = work & 127;
  const int n0   = (rem >> 3) * BN;   // 16 n-tiles
  const int m0   = (rem & 7) * BM;    // 8 m-tiles

  const __bf16* hA = h  + (size_t)(e * GT + m0) * ID;
  const float*  wB = w2 + (size_t)e * ID * HD;

  const int wid = t >> 6, lane = t & 63;
  const int wm = wid >> 1, wn = wid & 1;
  const int fr = lane & 15, fq = lane >> 4;

  f32x4 acc[4][4];
#pragma unroll
  for (int i = 0; i < 4; ++i)
#pragma unroll
    for (int j = 0; j < 4; ++j) acc[i][j] = 0.f;

  for (int k0 = 0; k0 < ID; k0 += BK) {
    // ---- stage A (bf16 direct): lane owns (m, k-octet). 1024 tasks, 4/thread.
#pragma unroll
    for (int i = 0; i < 4; ++i) {
      int id = i * 256 + t;
      int ko = id & 7, m = id >> 3;
      bf16x8 v = *reinterpret_cast<const bf16x8*>(hA + (size_t)m * ID + k0 + ko * 8);
      *reinterpret_cast<bf16x8*>(&As[m][(ko ^ (m & 7)) * 8]) = v;
    }
    // ---- stage B: lane owns (n-pair, k-octet). 512 tasks, 2/thread.
#pragma unroll
    for (int i = 0; i < 2; ++i) {
      int id = i * 256 + t;
      int np = id & 63, ko = id >> 6;
      const float* pg = wB + (size_t)(k0 + ko * 8) * HD + (n0 + np * 2);
      f32x2 r[8];
#pragma unroll
      for (int j = 0; j < 8; ++j)
        r[j] = *reinterpret_cast<const f32x2*>(pg + (size_t)j * HD);
      int slot = (ko ^ (np & 7)) * 8;
      bf16x8 v;
#pragma unroll
      for (int j = 0; j < 8; ++j) v[j] = f2b(r[j][0]);
      *reinterpret_cast<bf16x8*>(&Bs[np * 2][slot]) = v;
#pragma unroll
      for (int j = 0; j < 8; ++j) v[j] = f2b(r[j][1]);
      *reinterpret_cast<bf16x8*>(&Bs[np * 2 + 1][slot]) = v;
    }
    __syncthreads();
#pragma unroll
    for (int kk = 0; kk < BK; kk += 32) {
      const int kb = kk >> 3;
      bf16x8 af[4], bf[4];
#pragma unroll
      for (int mi = 0; mi < 4; ++mi) {
        int row = wm * 64 + mi * 16 + fr;
        int oct = (fq + kb) ^ (row & 7);
        af[mi] = *reinterpret_cast<const bf16x8*>(&As[row][oct * 8]);
      }
#pragma unroll
      for (int ni = 0; ni < 4; ++ni) {
        int row = wn * 64 + ni * 16 + fr;
        int oct = (fq + kb) ^ ((row >> 1) & 7);
        bf[ni] = *reinterpret_cast<const bf16x8*>(&Bs[row][oct * 8]);
      }
#pragma unroll
      for (int mi = 0; mi < 4; ++mi)
#pragma unroll
        for (int ni = 0; ni < 4; ++ni)
          acc[mi][ni] = __builtin_amdgcn_mfma_f32_16x16x32_bf16(af[mi], bf[ni], acc[mi][ni], 0, 0, 0);
    }
    __syncthreads();
  }

  // ---- epilogue: f32 store ----
#pragma unroll
  for (int mi = 0; mi < 4; ++mi)
#pragma unroll
    for (int ni = 0; ni < 4; ++ni)
#pragma unroll
      for (int j = 0; j < 4; ++j) {
        int row = m0 + wm * 64 + mi * 16 + fq * 4 + j;
        int col = n0 + wn * 64 + ni * 16 + fr;
        out[(size_t)(e * GT + row) * HD + col] = acc[mi][ni][j];
      }
}

extern "C" void kernel_launch(void* const* d_in, const int* in_sizes, int n_in,
                              void* d_out, int out_size, void* d_ws, size_t ws_size,
                              hipStream_t stream) {
  const float* x   = (const float*)d_in[0];
  const float* w13 = (const float*)d_in[1];
  const float* w2  = (const float*)d_in[2];
  float* out = (float*)d_out;
  __bf16* h = (__bf16*)d_ws;   // T x I bf16 = 64 MiB scratch

  moe_gemm1_swiglu<<<dim3(2048), dim3(256), 0, stream>>>(x, w13, h);
  moe_gemm2<<<dim3(4096), dim3(256), 0, stream>>>(h, w2, out);
}

// Round 3
// 812.908 us; speedup vs baseline: 1.2448x; 1.2448x over previous
//
#include <hip/hip_runtime.h>
#include <hip/hip_bf16.h>

// Problem constants (MoE grouped FFN, uniform groups)
#define NE 32      // experts
#define HD 2048    // hidden
#define ID 1024    // intermediate
#define GT 1024    // tokens per expert (T/E = 32768/32)

// Tile config
#define BM 128
#define BN 128
#define BK 64

typedef __attribute__((ext_vector_type(8))) __bf16 bf16x8;
typedef __attribute__((ext_vector_type(4))) float  f32x4;

__device__ __forceinline__ __bf16 f2b(float f) { return (__bf16)f; }

// ---------------------------------------------------------------------------
// Kernel 1: gate_up = x_e @ w13_e ; h = silu(gate)*up  (bf16 out to ws)
// grid (ID/BN=8, GT/BM=8, NE=32), 256 threads (4 waves 2x2).
// LDS XOR swizzle (verified conflict-free in R2):
//   A:  As[row][(oct ^ (row&7))*8 + j]
//   B:  Bg/Bu[row][(oct ^ ((row>>1)&7))*8 + j]
// Global loads: A = 2x f32x4 per (row,octet) -> 256B wave runs;
//               B = 8x f32x4 column walk per (n-quad,octet) -> 512B wave runs.
// ---------------------------------------------------------------------------
__global__ __launch_bounds__(256, 2)
void moe_gemm1_swiglu(const float* __restrict__ x,
                      const float* __restrict__ w13,
                      __bf16* __restrict__ h) {
  __shared__ __bf16 As[BM][BK];
  __shared__ __bf16 Bg[BN][BK];
  __shared__ __bf16 Bu[BN][BK];

  const int t  = threadIdx.x;
  const int e  = blockIdx.z;
  const int m0 = blockIdx.y * BM;
  const int n0 = blockIdx.x * BN;

  const float* xA = x   + (size_t)(e * GT + m0) * HD;
  const float* wB = w13 + (size_t)e * HD * (2 * ID);

  const int wid = t >> 6, lane = t & 63;
  const int wm = wid >> 1, wn = wid & 1;
  const int fr = lane & 15, fq = lane >> 4;

  // B staging ownership: one (n-quad, k-octet) task per thread
  const int nq = t & 31;        // n-quad 0..31  (4 cols each)
  const int ko = t >> 5;        // k-octet 0..7  (8 k-rows each)

  f32x4 accg[4][4];
  f32x4 accu[4][4];
#pragma unroll
  for (int i = 0; i < 4; ++i)
#pragma unroll
    for (int j = 0; j < 4; ++j) { accg[i][j] = 0.f; accu[i][j] = 0.f; }

  for (int k0 = 0; k0 < HD; k0 += BK) {
    // ---- stage A: 1024 tasks (row, k-octet), 4 per thread ----
#pragma unroll
    for (int i = 0; i < 4; ++i) {
      int id = i * 256 + t;
      int r = id >> 3, oc = id & 7;
      const float* src = xA + (size_t)r * HD + k0 + oc * 8;
      f32x4 a0 = *reinterpret_cast<const f32x4*>(src);
      f32x4 a1 = *reinterpret_cast<const f32x4*>(src + 4);
      bf16x8 v;
      v[0] = f2b(a0[0]); v[1] = f2b(a0[1]); v[2] = f2b(a0[2]); v[3] = f2b(a0[3]);
      v[4] = f2b(a1[0]); v[5] = f2b(a1[1]); v[6] = f2b(a1[2]); v[7] = f2b(a1[3]);
      *reinterpret_cast<bf16x8*>(&As[r][((oc ^ (r & 7)) * 8)]) = v;
    }
    // ---- stage B gate: 8x f32x4 column walk, transpose, 4 swizzled writes ----
    {
      const float* pg = wB + (size_t)(k0 + ko * 8) * (2 * ID) + (n0 + nq * 4);
      f32x4 g[8];
#pragma unroll
      for (int j = 0; j < 8; ++j)
        g[j] = *reinterpret_cast<const f32x4*>(pg + (size_t)j * (2 * ID));
#pragma unroll
      for (int c = 0; c < 4; ++c) {
        int row = nq * 4 + c;
        int slot = (ko ^ ((row >> 1) & 7)) * 8;
        bf16x8 v;
#pragma unroll
        for (int j = 0; j < 8; ++j) v[j] = f2b(g[j][c]);
        *reinterpret_cast<bf16x8*>(&Bg[row][slot]) = v;
      }
    }
    // ---- stage B up ----
    {
      const float* pu = wB + (size_t)(k0 + ko * 8) * (2 * ID) + ID + (n0 + nq * 4);
      f32x4 u[8];
#pragma unroll
      for (int j = 0; j < 8; ++j)
        u[j] = *reinterpret_cast<const f32x4*>(pu + (size_t)j * (2 * ID));
#pragma unroll
      for (int c = 0; c < 4; ++c) {
        int row = nq * 4 + c;
        int slot = (ko ^ ((row >> 1) & 7)) * 8;
        bf16x8 v;
#pragma unroll
        for (int j = 0; j < 8; ++j) v[j] = f2b(u[j][c]);
        *reinterpret_cast<bf16x8*>(&Bu[row][slot]) = v;
      }
    }
    __syncthreads();
    // ---- MFMA ----
#pragma unroll
    for (int kk = 0; kk < BK; kk += 32) {
      const int kb = kk >> 3;   // 0 or 4
      bf16x8 af[4], bgf[4], buf2[4];
#pragma unroll
      for (int mi = 0; mi < 4; ++mi) {
        int row = wm * 64 + mi * 16 + fr;
        int oct = (fq + kb) ^ (row & 7);
        af[mi] = *reinterpret_cast<const bf16x8*>(&As[row][oct * 8]);
      }
#pragma unroll
      for (int ni = 0; ni < 4; ++ni) {
        int row = wn * 64 + ni * 16 + fr;
        int oct = (fq + kb) ^ ((row >> 1) & 7);
        bgf[ni]  = *reinterpret_cast<const bf16x8*>(&Bg[row][oct * 8]);
        buf2[ni] = *reinterpret_cast<const bf16x8*>(&Bu[row][oct * 8]);
      }
#pragma unroll
      for (int mi = 0; mi < 4; ++mi)
#pragma unroll
        for (int ni = 0; ni < 4; ++ni) {
          accg[mi][ni] = __builtin_amdgcn_mfma_f32_16x16x32_bf16(af[mi], bgf[ni], accg[mi][ni], 0, 0, 0);
          accu[mi][ni] = __builtin_amdgcn_mfma_f32_16x16x32_bf16(af[mi], buf2[ni], accu[mi][ni], 0, 0, 0);
        }
    }
    __syncthreads();
  }

  // ---- epilogue: SwiGLU, write h (bf16) ----
#pragma unroll
  for (int mi = 0; mi < 4; ++mi)
#pragma unroll
    for (int ni = 0; ni < 4; ++ni)
#pragma unroll
      for (int j = 0; j < 4; ++j) {
        int row = m0 + wm * 64 + mi * 16 + fq * 4 + j;
        int col = n0 + wn * 64 + ni * 16 + fr;
        float g = accg[mi][ni][j];
        float u = accu[mi][ni][j];
        float s = g / (1.f + __expf(-g));
        h[(size_t)(e * GT + row) * ID + col] = f2b(s * u);
      }
}

// ---------------------------------------------------------------------------
// Kernel 2: out = h @ w2_e   (h bf16 [T][I], w2 f32 [E][I][H], out f32)
// grid (HD/BN=16, GT/BM=8, NE=32), 256 threads
// ---------------------------------------------------------------------------
__global__ __launch_bounds__(256, 3)
void moe_gemm2(const __bf16* __restrict__ h,
               const float* __restrict__ w2,
               float* __restrict__ out) {
  __shared__ __bf16 As[BM][BK];
  __shared__ __bf16 Bs[BN][BK];

  const int t  = threadIdx.x;
  const int e  = blockIdx.z;
  const int m0 = blockIdx.y * BM;
  const int n0 = blockIdx.x * BN;

  const __bf16* hA = h  + (size_t)(e * GT + m0) * ID;
  const float*  wB = w2 + (size_t)e * ID * HD;

  const int wid = t >> 6, lane = t & 63;
  const int wm = wid >> 1, wn = wid & 1;
  const int fr = lane & 15, fq = lane >> 4;

  const int nq = t & 31;
  const int ko = t >> 5;

  f32x4 acc[4][4];
#pragma unroll
  for (int i = 0; i < 4; ++i)
#pragma unroll
    for (int j = 0; j < 4; ++j) acc[i][j] = 0.f;

  for (int k0 = 0; k0 < ID; k0 += BK) {
    // ---- stage A (bf16 direct): (row, k-octet), 4 per thread ----
#pragma unroll
    for (int i = 0; i < 4; ++i) {
      int id = i * 256 + t;
      int koA = id & 7, m = id >> 3;
      bf16x8 v = *reinterpret_cast<const bf16x8*>(hA + (size_t)m * ID + k0 + koA * 8);
      *reinterpret_cast<bf16x8*>(&As[m][(koA ^ (m & 7)) * 8]) = v;
    }
    // ---- stage B: 8x f32x4 column walk, transpose, 4 swizzled writes ----
    {
      const float* pg = wB + (size_t)(k0 + ko * 8) * HD + (n0 + nq * 4);
      f32x4 r[8];
#pragma unroll
      for (int j = 0; j < 8; ++j)
        r[j] = *reinterpret_cast<const f32x4*>(pg + (size_t)j * HD);
#pragma unroll
      for (int c = 0; c < 4; ++c) {
        int row = nq * 4 + c;
        int slot = (ko ^ ((row >> 1) & 7)) * 8;
        bf16x8 v;
#pragma unroll
        for (int j = 0; j < 8; ++j) v[j] = f2b(r[j][c]);
        *reinterpret_cast<bf16x8*>(&Bs[row][slot]) = v;
      }
    }
    __syncthreads();
#pragma unroll
    for (int kk = 0; kk < BK; kk += 32) {
      const int kb = kk >> 3;
      bf16x8 af[4], bf[4];
#pragma unroll
      for (int mi = 0; mi < 4; ++mi) {
        int row = wm * 64 + mi * 16 + fr;
        int oct = (fq + kb) ^ (row & 7);
        af[mi] = *reinterpret_cast<const bf16x8*>(&As[row][oct * 8]);
      }
#pragma unroll
      for (int ni = 0; ni < 4; ++ni) {
        int row = wn * 64 + ni * 16 + fr;
        int oct = (fq + kb) ^ ((row >> 1) & 7);
        bf[ni] = *reinterpret_cast<const bf16x8*>(&Bs[row][oct * 8]);
      }
#pragma unroll
      for (int mi = 0; mi < 4; ++mi)
#pragma unroll
        for (int ni = 0; ni < 4; ++ni)
          acc[mi][ni] = __builtin_amdgcn_mfma_f32_16x16x32_bf16(af[mi], bf[ni], acc[mi][ni], 0, 0, 0);
    }
    __syncthreads();
  }

  // ---- epilogue: f32 store ----
#pragma unroll
  for (int mi = 0; mi < 4; ++mi)
#pragma unroll
    for (int ni = 0; ni < 4; ++ni)
#pragma unroll
      for (int j = 0; j < 4; ++j) {
        int row = m0 + wm * 64 + mi * 16 + fq * 4 + j;
        int col = n0 + wn * 64 + ni * 16 + fr;
        out[(size_t)(e * GT + row) * HD + col] = acc[mi][ni][j];
      }
}

extern "C" void kernel_launch(void* const* d_in, const int* in_sizes, int n_in,
                              void* d_out, int out_size, void* d_ws, size_t ws_size,
                              hipStream_t stream) {
  const float* x   = (const float*)d_in[0];
  const float* w13 = (const float*)d_in[1];
  const float* w2  = (const float*)d_in[2];
  float* out = (float*)d_out;
  __bf16* h = (__bf16*)d_ws;   // T x I bf16 = 64 MiB scratch

  moe_gemm1_swiglu<<<dim3(ID / BN, GT / BM, NE), dim3(256), 0, stream>>>(x, w13, h);
  moe_gemm2<<<dim3(HD / BN, GT / BM, NE), dim3(256), 0, stream>>>(h, w2, out);
}